// Round 1
// baseline (29359.891 us; speedup 1.0000x reference)
//
#include <hip/hip_runtime.h>
#include <hip/hip_bf16.h>
#include <math.h>

#define NS 2048
#define NTT 2048
#define NB 512
#define DIMX 256
#define NFEAT 8

// ---------------- small prep kernels ----------------

__global__ __launch_bounds__(256) void prep_k(const float* __restrict__ Wf,
                                              const float* __restrict__ bf,
                                              const float* __restrict__ Ws,
                                              const float* __restrict__ Wt,
                                              float* __restrict__ wcomb,
                                              float* __restrict__ consts) {
    int d = threadIdx.x;
    float w0 = 0.f, w1 = 0.f, w2 = 0.f, w3 = 0.f;
#pragma unroll
    for (int k = 0; k < NFEAT; ++k) {
        float wf = Wf[k * DIMX + d];
        w0 += Ws[k] * wf;
        w1 += Ws[NFEAT + k] * wf;
        w2 += Wt[k] * wf;
        w3 += Wt[NFEAT + k] * wf;
    }
    wcomb[0 * DIMX + d] = w0;
    wcomb[1 * DIMX + d] = w1;
    wcomb[2 * DIMX + d] = w2;
    wcomb[3 * DIMX + d] = w3;
    if (d == 0) {
        float c0 = 0.f, c1 = 0.f, c2 = 0.f, c3 = 0.f;
#pragma unroll
        for (int k = 0; k < NFEAT; ++k) {
            c0 += Ws[k] * bf[k];
            c1 += Ws[NFEAT + k] * bf[k];
            c2 += Wt[k] * bf[k];
            c3 += Wt[NFEAT + k] * bf[k];
        }
        consts[0] = c0; consts[1] = c1; consts[2] = c2; consts[3] = c3;
    }
}

__global__ __launch_bounds__(256) void matvec_k(const float* __restrict__ X, int nrows,
                                                const float* __restrict__ wc,
                                                const float* __restrict__ consts, int cidx,
                                                float* __restrict__ out) {
    int wave = threadIdx.x >> 6, lane = threadIdx.x & 63;
    int row = blockIdx.x * 4 + wave;
    if (row >= nrows) return;
    const float* xr = X + (size_t)row * DIMX;
    float s = 0.f;
#pragma unroll
    for (int t = 0; t < 4; ++t) s += xr[lane + 64 * t] * wc[lane + 64 * t];
#pragma unroll
    for (int off = 32; off; off >>= 1) s += __shfl_down(s, off);
    if (lane == 0) out[row] = s + consts[cidx];
}

__global__ __launch_bounds__(256) void weights_k(const float* __restrict__ a,
                                                 const float* __restrict__ b,
                                                 const float* __restrict__ bw,
                                                 float* __restrict__ w) {
    __shared__ float red[256];
    int i = blockIdx.x, tid = threadIdx.x;
    float ai = a[i] + bw[0];
    float r1 = ai + b[tid];
    float r2 = ai + b[tid + 256];
    float e1 = r1 > 0.f ? r1 : expm1f(r1);
    float e2 = r2 > 0.f ? r2 : expm1f(r2);
    red[tid] = e1 + e2;
    __syncthreads();
    for (int s = 128; s; s >>= 1) {
        if (tid < s) red[tid] += red[tid + s];
        __syncthreads();
    }
    float scale = 512.f / red[0];
    w[(size_t)i * NB + tid] = e1 * scale;
    w[(size_t)i * NB + tid + 256] = e2 * scale;
}

// ---------------- generic tiled f32 GEMM ----------------
// op(A)[i,k] = TA ? A[k*lda+i] : A[i*lda+k]
// op(B)[k,j] = TB ? B[j*ldb+k] : B[k*ldb+j]
// mode 0: C = acc
// mode 1: C = kmat*acc + diag(clip(noise))
// mode 2: C = kmat*acc
// mode 3: C = C - acc (in place)
template <int TA, int TB>
__global__ __launch_bounds__(256) void gemm_k(int M, int N, int K,
                                              const float* __restrict__ A, int lda,
                                              const float* __restrict__ B, int ldb,
                                              float* __restrict__ C, int ldc,
                                              const float* __restrict__ kmat, int ldk,
                                              const float* __restrict__ noisep,
                                              int mode, int row0, int col0, int lower_only) {
    __shared__ float As[16][65];
    __shared__ float Bs[16][65];
    int bm = blockIdx.y, bn = blockIdx.x;
    int rowBase = bm * 64, colBase = bn * 64;
    if (lower_only && (row0 + rowBase + 63) < (col0 + colBase)) return;
    int tid = threadIdx.x;
    int tx = tid & 15, ty = tid >> 4;
    float acc[4][4];
#pragma unroll
    for (int i = 0; i < 4; ++i)
#pragma unroll
        for (int j = 0; j < 4; ++j) acc[i][j] = 0.f;

    for (int kk = 0; kk < K; kk += 16) {
        if (TA == 0) {
#pragma unroll
            for (int t = tid; t < 64 * 16; t += 256) {
                int k = t & 15, i = t >> 4;
                int gi = rowBase + i, gk = kk + k;
                As[k][i] = (gi < M && gk < K) ? A[(size_t)gi * lda + gk] : 0.f;
            }
        } else {
#pragma unroll
            for (int t = tid; t < 64 * 16; t += 256) {
                int i = t & 63, k = t >> 6;
                int gi = rowBase + i, gk = kk + k;
                As[k][i] = (gi < M && gk < K) ? A[(size_t)gk * lda + gi] : 0.f;
            }
        }
        if (TB == 0) {
#pragma unroll
            for (int t = tid; t < 64 * 16; t += 256) {
                int j = t & 63, k = t >> 6;
                int gj = colBase + j, gk = kk + k;
                Bs[k][j] = (gj < N && gk < K) ? B[(size_t)gk * ldb + gj] : 0.f;
            }
        } else {
#pragma unroll
            for (int t = tid; t < 64 * 16; t += 256) {
                int k = t & 15, j = t >> 4;
                int gj = colBase + j, gk = kk + k;
                Bs[k][j] = (gj < N && gk < K) ? B[(size_t)gj * ldb + gk] : 0.f;
            }
        }
        __syncthreads();
#pragma unroll
        for (int k = 0; k < 16; ++k) {
            float a0 = As[k][ty * 4 + 0], a1 = As[k][ty * 4 + 1];
            float a2 = As[k][ty * 4 + 2], a3 = As[k][ty * 4 + 3];
            float b0 = Bs[k][tx * 4 + 0], b1 = Bs[k][tx * 4 + 1];
            float b2 = Bs[k][tx * 4 + 2], b3 = Bs[k][tx * 4 + 3];
            acc[0][0] += a0 * b0; acc[0][1] += a0 * b1; acc[0][2] += a0 * b2; acc[0][3] += a0 * b3;
            acc[1][0] += a1 * b0; acc[1][1] += a1 * b1; acc[1][2] += a1 * b2; acc[1][3] += a1 * b3;
            acc[2][0] += a2 * b0; acc[2][1] += a2 * b1; acc[2][2] += a2 * b2; acc[2][3] += a2 * b3;
            acc[3][0] += a3 * b0; acc[3][1] += a3 * b1; acc[3][2] += a3 * b2; acc[3][3] += a3 * b3;
        }
        __syncthreads();
    }
#pragma unroll
    for (int i = 0; i < 4; ++i) {
#pragma unroll
        for (int j = 0; j < 4; ++j) {
            int gi = rowBase + ty * 4 + i, gj = colBase + tx * 4 + j;
            if (gi < M && gj < N) {
                float v = acc[i][j];
                if (mode == 1 || mode == 2) {
                    v *= kmat[(size_t)gi * ldk + gj];
                    if (mode == 1 && (row0 + gi) == (col0 + gj)) {
                        float ns = noisep[0];
                        ns = fminf(fmaxf(ns, 1e-5f), 1.0f);
                        v += ns;
                    }
                } else if (mode == 3) {
                    v = C[(size_t)gi * ldc + gj] - v;
                }
                C[(size_t)gi * ldc + gj] = v;
            }
        }
    }
}

// ---------------- Cholesky building blocks (BS=64) ----------------

__global__ __launch_bounds__(64) void chol_diag_k(float* __restrict__ A, int lda) {
    __shared__ float s[64][65];
    int tid = threadIdx.x;
    for (int r = 0; r < 64; ++r) s[r][tid] = A[(size_t)r * lda + tid];
    __syncthreads();
    for (int k = 0; k < 64; ++k) {
        float dk = sqrtf(s[k][k]);
        float inv = 1.0f / dk;
        if (tid == k) s[k][k] = dk;
        if (tid > k) s[tid][k] *= inv;
        __syncthreads();
        if (tid > k) {
            float aik = s[tid][k];
            for (int j = k + 1; j <= tid; ++j) s[tid][j] -= aik * s[j][k];
        }
        __syncthreads();
    }
    for (int r = 0; r < 64; ++r) A[(size_t)r * lda + tid] = s[r][tid];
}

__global__ __launch_bounds__(64) void chol_panel_k(const float* __restrict__ Ld, int lda,
                                                   float* __restrict__ P) {
    __shared__ float Lk[64][65];
    __shared__ float T[64][65];
    int tid = threadIdx.x;
    float* Pb = P + (size_t)blockIdx.x * 64 * lda;
    for (int r = 0; r < 64; ++r) {
        Lk[r][tid] = Ld[(size_t)r * lda + tid];
        T[r][tid] = Pb[(size_t)r * lda + tid];
    }
    __syncthreads();
    for (int c = 0; c < 64; ++c) {
        float acc = T[tid][c];
        for (int d = 0; d < c; ++d) acc -= T[tid][d] * Lk[c][d];
        T[tid][c] = acc / Lk[c][c];
    }
    __syncthreads();
    for (int r = 0; r < 64; ++r) Pb[(size_t)r * lda + tid] = T[r][tid];
}

__global__ __launch_bounds__(64) void trsm_fwd_k(const float* __restrict__ Ld, int lda,
                                                 float* __restrict__ X, int ldx) {
    __shared__ float Lk[64][65];
    __shared__ float xs[64][64];
    int tid = threadIdx.x;
    for (int r = 0; r < 64; ++r) Lk[r][tid] = Ld[(size_t)r * lda + tid];
    int j0 = blockIdx.x * 64;
    for (int r = 0; r < 64; ++r) xs[r][tid] = X[(size_t)r * ldx + j0 + tid];
    __syncthreads();
    for (int r = 0; r < 64; ++r) {
        float acc = xs[r][tid];
        for (int s = 0; s < r; ++s) acc -= Lk[r][s] * xs[s][tid];
        xs[r][tid] = acc / Lk[r][r];
    }
    for (int r = 0; r < 64; ++r) X[(size_t)r * ldx + j0 + tid] = xs[r][tid];
}

__global__ __launch_bounds__(64) void trsm_bwd_k(const float* __restrict__ Ld, int lda,
                                                 float* __restrict__ X, int ldx) {
    __shared__ float Lk[64][65];
    __shared__ float xs[64][64];
    int tid = threadIdx.x;
    for (int r = 0; r < 64; ++r) Lk[r][tid] = Ld[(size_t)r * lda + tid];
    int j0 = blockIdx.x * 64;
    for (int r = 0; r < 64; ++r) xs[r][tid] = X[(size_t)r * ldx + j0 + tid];
    __syncthreads();
    for (int r = 63; r >= 0; --r) {
        float acc = xs[r][tid];
        for (int s = r + 1; s < 64; ++s) acc -= Lk[s][r] * xs[s][tid];
        xs[r][tid] = acc / Lk[r][r];
    }
    for (int r = 0; r < 64; ++r) X[(size_t)r * ldx + j0 + tid] = xs[r][tid];
}

__global__ __launch_bounds__(256) void resid_k(const float* __restrict__ W, int n,
                                               const float* __restrict__ sy,
                                               const float* __restrict__ ty,
                                               float* __restrict__ r) {
    int j = blockIdx.x * 256 + threadIdx.x;
    float acc = 0.f;
    for (int i = 0; i < n; ++i) acc += W[(size_t)i * n + j] * sy[i];
    r[j] = ty[j] - acc;
}

__global__ __launch_bounds__(64) void trsv_fwd_k(const float* __restrict__ L, int n, int ldl,
                                                 const float* __restrict__ rhs,
                                                 float* __restrict__ v) {
    __shared__ float vs[NS];
    int lane = threadIdx.x;
    for (int i = 0; i < n; ++i) {
        float partial = 0.f;
        for (int j = lane; j < i; j += 64) partial += L[(size_t)i * ldl + j] * vs[j];
#pragma unroll
        for (int off = 32; off; off >>= 1) partial += __shfl_down(partial, off);
        if (lane == 0) vs[i] = (rhs[i] - partial) / L[(size_t)i * ldl + i];
        __syncthreads();
    }
    for (int i = lane; i < n; i += 64) v[i] = vs[i];
}

__global__ __launch_bounds__(256) void loss_k(const float* __restrict__ Lc, int n, int ldl,
                                              const float* __restrict__ v,
                                              float* __restrict__ out) {
    __shared__ float red1[256];
    __shared__ float red2[256];
    int tid = threadIdx.x;
    float s1 = 0.f, s2 = 0.f;
    for (int i = tid; i < n; i += 256) {
        s1 += logf(Lc[(size_t)i * ldl + i]);
        float vi = v[i];
        s2 += vi * vi;
    }
    red1[tid] = s1;
    red2[tid] = s2;
    __syncthreads();
    for (int s = 128; s; s >>= 1) {
        if (tid < s) { red1[tid] += red1[tid + s]; red2[tid] += red2[tid + s]; }
        __syncthreads();
    }
    if (tid == 0) {
        out[0] = 0.5f * red1[0] + 0.5f * red2[0] + 0.5f * (float)n * 1.8378770664093453f;
    }
}

// ---------------- host orchestration ----------------

static void run_chol(float* A, hipStream_t stream) {
    for (int kb = 0; kb < 32; ++kb) {
        float* Ld = A + (size_t)kb * 64 * NS + kb * 64;
        chol_diag_k<<<1, 64, 0, stream>>>(Ld, NS);
        int nbelow = 31 - kb;
        if (nbelow > 0) {
            float* P = A + (size_t)(kb + 1) * 64 * NS + kb * 64;
            chol_panel_k<<<dim3(nbelow), 64, 0, stream>>>(Ld, NS, P);
        }
        int rem = NS - (kb + 1) * 64;
        if (rem > 0) {
            float* P = A + (size_t)(kb + 1) * 64 * NS + kb * 64;
            float* Ct = A + (size_t)(kb + 1) * 64 * NS + (kb + 1) * 64;
            dim3 g(rem / 64, rem / 64);
            gemm_k<0, 1><<<g, 256, 0, stream>>>(rem, rem, 64, P, NS, P, NS, Ct, NS,
                                                nullptr, 0, nullptr, 3,
                                                (kb + 1) * 64, (kb + 1) * 64, 1);
        }
    }
}

extern "C" void kernel_launch(void* const* d_in, const int* in_sizes, int n_in,
                              void* d_out, int out_size, void* d_ws, size_t ws_size,
                              hipStream_t stream) {
    const float* source_x = (const float*)d_in[0];
    const float* source_y = (const float*)d_in[1];
    const float* target_x = (const float*)d_in[2];
    const float* target_y = (const float*)d_in[3];
    const float* k_ss = (const float*)d_in[4];
    const float* k_tt = (const float*)d_in[5];
    const float* k_st = (const float*)d_in[6];
    const float* noise_s = (const float*)d_in[7];
    const float* noise_t = (const float*)d_in[8];
    const float* Wf = (const float*)d_in[9];
    const float* bf = (const float*)d_in[10];
    const float* Ws = (const float*)d_in[11];
    const float* bs = (const float*)d_in[12];
    const float* Wt = (const float*)d_in[13];
    const float* bt = (const float*)d_in[14];
    const float* Kb = (const float*)d_in[15];
    const float* base_s = (const float*)d_in[16];
    const float* base_t = (const float*)d_in[17];
    float* out = (float*)d_out;

    float* w = (float*)d_ws;
    const size_t M2 = (size_t)NS * NS;
    float* Ksrc = w;
    float* Kcos = w + M2;
    float* Ktgt = w + 2 * M2;
    float* stag = w + 3 * M2;
    float* wsb = stag;
    float* wtb = stag + (size_t)NS * NB;
    float* wsK = stag + 2 * (size_t)NS * NB;
    float* wtK = stag + 3 * (size_t)NS * NB;
    float* W = stag; // overlays staging after staging is consumed
    float* sm = w + 4 * M2;
    float* wcomb = sm;
    float* consts = sm + 1024;
    float* a_s = sm + 1028;
    float* b_s = a_s + NS;
    float* a_t = b_s + NB;
    float* b_t = a_t + NS;
    float* rvec = b_t + NB;
    float* vvec = rvec + NS;

    prep_k<<<1, 256, 0, stream>>>(Wf, bf, Ws, Wt, wcomb, consts);
    matvec_k<<<NS / 4, 256, 0, stream>>>(source_x, NS, wcomb + 0 * DIMX, consts, 0, a_s);
    matvec_k<<<NB / 4, 256, 0, stream>>>(base_s, NB, wcomb + 1 * DIMX, consts, 1, b_s);
    matvec_k<<<NS / 4, 256, 0, stream>>>(target_x, NS, wcomb + 2 * DIMX, consts, 2, a_t);
    matvec_k<<<NB / 4, 256, 0, stream>>>(base_t, NB, wcomb + 3 * DIMX, consts, 3, b_t);
    weights_k<<<NS, 256, 0, stream>>>(a_s, b_s, bs, wsb);
    weights_k<<<NS, 256, 0, stream>>>(a_t, b_t, bt, wtb);

    {
        dim3 g(NB / 64, NS / 64);
        gemm_k<0, 0><<<g, 256, 0, stream>>>(NS, NB, NB, wsb, NB, Kb, NB, wsK, NB,
                                            nullptr, 0, nullptr, 0, 0, 0, 0);
        gemm_k<0, 0><<<g, 256, 0, stream>>>(NS, NB, NB, wtb, NB, Kb, NB, wtK, NB,
                                            nullptr, 0, nullptr, 0, 0, 0, 0);
    }
    {
        dim3 g(NS / 64, NS / 64);
        gemm_k<0, 1><<<g, 256, 0, stream>>>(NS, NS, NB, wsK, NB, wsb, NB, Ksrc, NS,
                                            k_ss, NS, noise_s, 1, 0, 0, 0);
        gemm_k<0, 1><<<g, 256, 0, stream>>>(NS, NS, NB, wtK, NB, wtb, NB, Ktgt, NS,
                                            k_tt, NS, noise_t, 1, 0, 0, 0);
        gemm_k<0, 1><<<g, 256, 0, stream>>>(NS, NS, NB, wsK, NB, wtb, NB, Kcos, NS,
                                            k_st, NS, nullptr, 2, 0, 0, 0);
    }

    run_chol(Ksrc, stream);

    hipMemcpyAsync(W, Kcos, M2 * sizeof(float), hipMemcpyDeviceToDevice, stream);
    for (int ib = 0; ib < 32; ++ib) {
        if (ib > 0) {
            dim3 g(NS / 64, 1);
            gemm_k<0, 0><<<g, 256, 0, stream>>>(64, NS, ib * 64,
                                                Ksrc + (size_t)ib * 64 * NS, NS,
                                                W, NS,
                                                W + (size_t)ib * 64 * NS, NS,
                                                nullptr, 0, nullptr, 3, 0, 0, 0);
        }
        trsm_fwd_k<<<NS / 64, 64, 0, stream>>>(Ksrc + (size_t)ib * 64 * NS + ib * 64, NS,
                                               W + (size_t)ib * 64 * NS, NS);
    }
    for (int ib = 31; ib >= 0; --ib) {
        if (ib < 31) {
            int base = (ib + 1) * 64;
            dim3 g(NS / 64, 1);
            gemm_k<1, 0><<<g, 256, 0, stream>>>(64, NS, NS - base,
                                                Ksrc + (size_t)base * NS + ib * 64, NS,
                                                W + (size_t)base * NS, NS,
                                                W + (size_t)ib * 64 * NS, NS,
                                                nullptr, 0, nullptr, 3, 0, 0, 0);
        }
        trsm_bwd_k<<<NS / 64, 64, 0, stream>>>(Ksrc + (size_t)ib * 64 * NS + ib * 64, NS,
                                               W + (size_t)ib * 64 * NS, NS);
    }

    {
        dim3 g(NS / 64, NS / 64);
        gemm_k<1, 0><<<g, 256, 0, stream>>>(NS, NS, NS, Kcos, NS, W, NS, Ktgt, NS,
                                            nullptr, 0, nullptr, 3, 0, 0, 0);
    }

    resid_k<<<NS / 256, 256, 0, stream>>>(W, NS, source_y, target_y, rvec);

    run_chol(Ktgt, stream);

    trsv_fwd_k<<<1, 64, 0, stream>>>(Ktgt, NS, NS, rvec, vvec);

    loss_k<<<1, 256, 0, stream>>>(Ktgt, NS, NS, vvec, out);
}

// Round 2
// 22059.373 us; speedup vs baseline: 1.3309x; 1.3309x over previous
//
#include <hip/hip_runtime.h>
#include <hip/hip_bf16.h>
#include <math.h>

#define NS 2048
#define NB 512
#define DIMX 256
#define NFEAT 8

// ---------------- small prep kernels ----------------

__global__ __launch_bounds__(256) void prep_k(const float* __restrict__ Wf,
                                              const float* __restrict__ bf,
                                              const float* __restrict__ Ws,
                                              const float* __restrict__ Wt,
                                              float* __restrict__ wcomb,
                                              float* __restrict__ consts) {
    int d = threadIdx.x;
    float w0 = 0.f, w1 = 0.f, w2 = 0.f, w3 = 0.f;
#pragma unroll
    for (int k = 0; k < NFEAT; ++k) {
        float wf = Wf[k * DIMX + d];
        w0 += Ws[k] * wf;
        w1 += Ws[NFEAT + k] * wf;
        w2 += Wt[k] * wf;
        w3 += Wt[NFEAT + k] * wf;
    }
    wcomb[0 * DIMX + d] = w0;
    wcomb[1 * DIMX + d] = w1;
    wcomb[2 * DIMX + d] = w2;
    wcomb[3 * DIMX + d] = w3;
    if (d == 0) {
        float c0 = 0.f, c1 = 0.f, c2 = 0.f, c3 = 0.f;
#pragma unroll
        for (int k = 0; k < NFEAT; ++k) {
            c0 += Ws[k] * bf[k];
            c1 += Ws[NFEAT + k] * bf[k];
            c2 += Wt[k] * bf[k];
            c3 += Wt[NFEAT + k] * bf[k];
        }
        consts[0] = c0; consts[1] = c1; consts[2] = c2; consts[3] = c3;
    }
}

__global__ __launch_bounds__(256) void matvec_k(const float* __restrict__ X, int nrows,
                                                const float* __restrict__ wc,
                                                const float* __restrict__ consts, int cidx,
                                                float* __restrict__ out) {
    int wave = threadIdx.x >> 6, lane = threadIdx.x & 63;
    int row = blockIdx.x * 4 + wave;
    if (row >= nrows) return;
    const float* xr = X + (size_t)row * DIMX;
    float s = 0.f;
#pragma unroll
    for (int t = 0; t < 4; ++t) s += xr[lane + 64 * t] * wc[lane + 64 * t];
#pragma unroll
    for (int off = 32; off; off >>= 1) s += __shfl_down(s, off);
    if (lane == 0) out[row] = s + consts[cidx];
}

__global__ __launch_bounds__(256) void weights_k(const float* __restrict__ a,
                                                 const float* __restrict__ b,
                                                 const float* __restrict__ bw,
                                                 float* __restrict__ w) {
    __shared__ float red[256];
    int i = blockIdx.x, tid = threadIdx.x;
    float ai = a[i] + bw[0];
    float r1 = ai + b[tid];
    float r2 = ai + b[tid + 256];
    float e1 = r1 > 0.f ? r1 : expm1f(r1);
    float e2 = r2 > 0.f ? r2 : expm1f(r2);
    red[tid] = e1 + e2;
    __syncthreads();
    for (int s = 128; s; s >>= 1) {
        if (tid < s) red[tid] += red[tid + s];
        __syncthreads();
    }
    float scale = 512.f / red[0];
    w[(size_t)i * NB + tid] = e1 * scale;
    w[(size_t)i * NB + tid + 256] = e2 * scale;
}

// ---------------- 64-tile f32 GEMM (thin work, batched-z) ----------------
// mode 0: C=acc | 1: C=kmat*acc+diag(noise) | 2: C=kmat*acc | 3: C=C-acc | 4: C=-acc
template <int TA, int TB>
__global__ __launch_bounds__(256) void gemm64_k(int M, int N, int K,
                                                const float* __restrict__ A, int lda, size_t zoffA,
                                                const float* __restrict__ B, int ldb, size_t zoffB,
                                                float* __restrict__ C, int ldc, size_t zoffC,
                                                const float* __restrict__ kmat, int ldk,
                                                const float* __restrict__ noisep,
                                                int mode, int row0, int col0, int lower_only) {
    __shared__ float As[16][65];
    __shared__ float Bs[16][65];
    int bz = blockIdx.z;
    A += zoffA * bz; B += zoffB * bz; C += zoffC * bz;
    int bm = blockIdx.y, bn = blockIdx.x;
    int rowBase = bm * 64, colBase = bn * 64;
    if (lower_only && (row0 + rowBase + 63) < (col0 + colBase)) return;
    int tid = threadIdx.x;
    int tx = tid & 15, ty = tid >> 4;
    float acc[4][4];
#pragma unroll
    for (int i = 0; i < 4; ++i)
#pragma unroll
        for (int j = 0; j < 4; ++j) acc[i][j] = 0.f;

    for (int kk = 0; kk < K; kk += 16) {
        if (TA == 0) {
#pragma unroll
            for (int t = tid; t < 64 * 16; t += 256) {
                int k = t & 15, i = t >> 4;
                int gi = rowBase + i, gk = kk + k;
                As[k][i] = (gi < M && gk < K) ? A[(size_t)gi * lda + gk] : 0.f;
            }
        } else {
#pragma unroll
            for (int t = tid; t < 64 * 16; t += 256) {
                int i = t & 63, k = t >> 6;
                int gi = rowBase + i, gk = kk + k;
                As[k][i] = (gi < M && gk < K) ? A[(size_t)gk * lda + gi] : 0.f;
            }
        }
        if (TB == 0) {
#pragma unroll
            for (int t = tid; t < 64 * 16; t += 256) {
                int j = t & 63, k = t >> 6;
                int gj = colBase + j, gk = kk + k;
                Bs[k][j] = (gj < N && gk < K) ? B[(size_t)gk * ldb + gj] : 0.f;
            }
        } else {
#pragma unroll
            for (int t = tid; t < 64 * 16; t += 256) {
                int k = t & 15, j = t >> 4;
                int gj = colBase + j, gk = kk + k;
                Bs[k][j] = (gj < N && gk < K) ? B[(size_t)gj * ldb + gk] : 0.f;
            }
        }
        __syncthreads();
#pragma unroll
        for (int k = 0; k < 16; ++k) {
            float a0 = As[k][ty * 4 + 0], a1 = As[k][ty * 4 + 1];
            float a2 = As[k][ty * 4 + 2], a3 = As[k][ty * 4 + 3];
            float b0 = Bs[k][tx * 4 + 0], b1 = Bs[k][tx * 4 + 1];
            float b2 = Bs[k][tx * 4 + 2], b3 = Bs[k][tx * 4 + 3];
            acc[0][0] += a0 * b0; acc[0][1] += a0 * b1; acc[0][2] += a0 * b2; acc[0][3] += a0 * b3;
            acc[1][0] += a1 * b0; acc[1][1] += a1 * b1; acc[1][2] += a1 * b2; acc[1][3] += a1 * b3;
            acc[2][0] += a2 * b0; acc[2][1] += a2 * b1; acc[2][2] += a2 * b2; acc[2][3] += a2 * b3;
            acc[3][0] += a3 * b0; acc[3][1] += a3 * b1; acc[3][2] += a3 * b2; acc[3][3] += a3 * b3;
        }
        __syncthreads();
    }
#pragma unroll
    for (int i = 0; i < 4; ++i) {
#pragma unroll
        for (int j = 0; j < 4; ++j) {
            int gi = rowBase + ty * 4 + i, gj = colBase + tx * 4 + j;
            if (gi < M && gj < N) {
                float v = acc[i][j];
                if (mode == 1 || mode == 2) {
                    v *= kmat[(size_t)gi * ldk + gj];
                    if (mode == 1 && (row0 + gi) == (col0 + gj)) {
                        float ns = noisep[0];
                        ns = fminf(fmaxf(ns, 1e-5f), 1.0f);
                        v += ns;
                    }
                } else if (mode == 3) {
                    v = C[(size_t)gi * ldc + gj] - v;
                } else if (mode == 4) {
                    v = -v;
                }
                C[(size_t)gi * ldc + gj] = v;
            }
        }
    }
}

// ---------------- 128-tile f32 GEMM (exact multiples of 128 in M,N; K mult of 16) ----
// flags bit0 = lower_only (skip tiles strictly above diagonal)
// flags bit1 = ktrim (K limited to rowBase+128; for lower-triangular A)
template <int TA, int TB>
__global__ __launch_bounds__(256) void gemm128_k(int M, int N, int K,
                                                 const float* __restrict__ A, int lda, size_t zoffA,
                                                 const float* __restrict__ B, int ldb, size_t zoffB,
                                                 float* __restrict__ C, int ldc, size_t zoffC,
                                                 const float* __restrict__ kmat, int ldk,
                                                 const float* __restrict__ noisep,
                                                 int mode, int row0, int col0, int flags) {
    __shared__ float As[16][132];
    __shared__ float Bs[16][132];
    int bz = blockIdx.z;
    A += zoffA * bz; B += zoffB * bz; C += zoffC * bz;
    int bm = blockIdx.y, bn = blockIdx.x;
    int rowBase = bm * 128, colBase = bn * 128;
    if ((flags & 1) && (rowBase + 127) < colBase) return;
    int Kend = (flags & 2) ? ((rowBase + 128 < K) ? rowBase + 128 : K) : K;
    int tid = threadIdx.x;
    int tx = tid & 15, ty = tid >> 4;
    float acc[8][8];
#pragma unroll
    for (int i = 0; i < 8; ++i)
#pragma unroll
        for (int j = 0; j < 8; ++j) acc[i][j] = 0.f;

    for (int kk = 0; kk < Kend; kk += 16) {
        if (TA == 0) {
            int row = tid >> 1, koff = (tid & 1) * 8;
            const float* src = A + (size_t)(rowBase + row) * lda + kk + koff;
            float4 v0 = *(const float4*)(src);
            float4 v1 = *(const float4*)(src + 4);
            As[koff + 0][row] = v0.x; As[koff + 1][row] = v0.y;
            As[koff + 2][row] = v0.z; As[koff + 3][row] = v0.w;
            As[koff + 4][row] = v1.x; As[koff + 5][row] = v1.y;
            As[koff + 6][row] = v1.z; As[koff + 7][row] = v1.w;
        } else {
            int k = tid >> 4, ib = (tid & 15) * 4;
            const float* src = A + (size_t)(kk + k) * lda + rowBase + ib;
            *(float4*)&As[k][ib] = *(const float4*)src;
            *(float4*)&As[k][ib + 64] = *(const float4*)(src + 64);
        }
        if (TB == 0) {
            int k = tid >> 4, jb = (tid & 15) * 4;
            const float* src = B + (size_t)(kk + k) * ldb + colBase + jb;
            *(float4*)&Bs[k][jb] = *(const float4*)src;
            *(float4*)&Bs[k][jb + 64] = *(const float4*)(src + 64);
        } else {
            int col = tid >> 1, koff = (tid & 1) * 8;
            const float* src = B + (size_t)(colBase + col) * ldb + kk + koff;
            float4 v0 = *(const float4*)(src);
            float4 v1 = *(const float4*)(src + 4);
            Bs[koff + 0][col] = v0.x; Bs[koff + 1][col] = v0.y;
            Bs[koff + 2][col] = v0.z; Bs[koff + 3][col] = v0.w;
            Bs[koff + 4][col] = v1.x; Bs[koff + 5][col] = v1.y;
            Bs[koff + 6][col] = v1.z; Bs[koff + 7][col] = v1.w;
        }
        __syncthreads();
#pragma unroll
        for (int k = 0; k < 16; ++k) {
            float a[8], b[8];
            float4 t0 = *(const float4*)&As[k][ty * 4];
            float4 t1 = *(const float4*)&As[k][64 + ty * 4];
            float4 u0 = *(const float4*)&Bs[k][tx * 4];
            float4 u1 = *(const float4*)&Bs[k][64 + tx * 4];
            a[0] = t0.x; a[1] = t0.y; a[2] = t0.z; a[3] = t0.w;
            a[4] = t1.x; a[5] = t1.y; a[6] = t1.z; a[7] = t1.w;
            b[0] = u0.x; b[1] = u0.y; b[2] = u0.z; b[3] = u0.w;
            b[4] = u1.x; b[5] = u1.y; b[6] = u1.z; b[7] = u1.w;
#pragma unroll
            for (int i = 0; i < 8; ++i)
#pragma unroll
                for (int j = 0; j < 8; ++j) acc[i][j] += a[i] * b[j];
        }
        __syncthreads();
    }
#pragma unroll
    for (int i = 0; i < 8; ++i) {
        int gi = rowBase + ((i >> 2) << 6) + ty * 4 + (i & 3);
#pragma unroll
        for (int j = 0; j < 8; ++j) {
            int gj = colBase + ((j >> 2) << 6) + tx * 4 + (j & 3);
            float v = acc[i][j];
            if (mode == 1 || mode == 2) {
                v *= kmat[(size_t)gi * ldk + gj];
                if (mode == 1 && (row0 + gi) == (col0 + gj)) {
                    float ns = noisep[0];
                    ns = fminf(fmaxf(ns, 1e-5f), 1.0f);
                    v += ns;
                }
            } else if (mode == 3) {
                v = C[(size_t)gi * ldc + gj] - v;
            } else if (mode == 4) {
                v = -v;
            }
            C[(size_t)gi * ldc + gj] = v;
        }
    }
}

// ---------------- fused 64x64 diag Cholesky + triangular inverse ----------------
// storeL=1: write L back to A, Dinv to dinv. storeL=0: write only Dinv (dinv may be A).
__global__ __launch_bounds__(64) void chol_diag_inv_k(float* __restrict__ A, int lda,
                                                      float* __restrict__ dinv, int dld,
                                                      int storeL) {
    __shared__ float s[64][65];
    __shared__ float X[64][65];
    int tid = threadIdx.x;
    for (int r = 0; r < 64; ++r) s[r][tid] = A[(size_t)r * lda + tid];
    __syncthreads();
    for (int k = 0; k < 64; ++k) {
        float dk = sqrtf(s[k][k]);
        float inv = 1.0f / dk;
        if (tid == k) s[k][k] = dk;
        if (tid > k) s[tid][k] *= inv;
        __syncthreads();
        if (tid > k) {
            float aik = s[tid][k];
            for (int j = k + 1; j <= tid; ++j) s[tid][j] -= aik * s[j][k];
        }
        __syncthreads();
    }
    // invert lower-tri L (in s): column tid of X = L^{-1}
    for (int r = 0; r < 64; ++r) {
        if (r < tid) {
            X[r][tid] = 0.f;
        } else if (r == tid) {
            X[r][tid] = 1.0f / s[r][r];
        } else {
            float acc = 0.f;
            for (int t = tid; t < r; ++t) acc -= s[r][t] * X[t][tid];
            X[r][tid] = acc / s[r][r];
        }
    }
    if (storeL) {
        for (int r = 0; r < 64; ++r) A[(size_t)r * lda + tid] = s[r][tid];
    }
    for (int r = 0; r < 64; ++r) dinv[(size_t)r * dld + tid] = X[r][tid];
}

__global__ __launch_bounds__(256) void zero_upper_k(float* __restrict__ A, int n, int lda) {
    int i = blockIdx.x;
    for (int j = i + 1 + threadIdx.x; j < n; j += 256) A[(size_t)i * lda + j] = 0.f;
}

// z[row] = sum_{j<=row} L[row][j] * y[j]
__global__ __launch_bounds__(256) void gemv_lower_k(const float* __restrict__ L, int ld,
                                                    const float* __restrict__ y,
                                                    float* __restrict__ z, int n) {
    int wave = threadIdx.x >> 6, lane = threadIdx.x & 63;
    int row = blockIdx.x * 4 + wave;
    if (row >= n) return;
    const float* Lr = L + (size_t)row * ld;
    float s = 0.f;
    for (int j = lane; j <= row; j += 64) s += Lr[j] * y[j];
#pragma unroll
    for (int off = 32; off; off >>= 1) s += __shfl_down(s, off);
    if (lane == 0) z[row] = s;
}

// r[j] = ty[j] - sum_i Z[i][j] * zv[i]
__global__ __launch_bounds__(256) void resid_k(const float* __restrict__ Z, int n,
                                               const float* __restrict__ zv,
                                               const float* __restrict__ ty,
                                               float* __restrict__ r) {
    int j = blockIdx.x * 256 + threadIdx.x;
    float acc = 0.f;
    for (int i = 0; i < n; ++i) acc += Z[(size_t)i * n + j] * zv[i];
    r[j] = ty[j] - acc;
}

__global__ __launch_bounds__(64) void trsv_fwd_k(const float* __restrict__ L, int n, int ldl,
                                                 const float* __restrict__ rhs,
                                                 float* __restrict__ v) {
    __shared__ float vs[NS];
    int lane = threadIdx.x;
    for (int i = 0; i < n; ++i) {
        float partial = 0.f;
        for (int j = lane; j < i; j += 64) partial += L[(size_t)i * ldl + j] * vs[j];
#pragma unroll
        for (int off = 32; off; off >>= 1) partial += __shfl_down(partial, off);
        if (lane == 0) vs[i] = (rhs[i] - partial) / L[(size_t)i * ldl + i];
        __syncthreads();
    }
    for (int i = lane; i < n; i += 64) v[i] = vs[i];
}

__global__ __launch_bounds__(256) void loss_k(const float* __restrict__ Lc, int n, int ldl,
                                              const float* __restrict__ v,
                                              float* __restrict__ out) {
    __shared__ float red1[256];
    __shared__ float red2[256];
    int tid = threadIdx.x;
    float s1 = 0.f, s2 = 0.f;
    for (int i = tid; i < n; i += 256) {
        s1 += logf(Lc[(size_t)i * ldl + i]);
        float vi = v[i];
        s2 += vi * vi;
    }
    red1[tid] = s1;
    red2[tid] = s2;
    __syncthreads();
    for (int s = 128; s; s >>= 1) {
        if (tid < s) { red1[tid] += red1[tid + s]; red2[tid] += red2[tid + s]; }
        __syncthreads();
    }
    if (tid == 0) {
        out[0] = 0.5f * red1[0] + 0.5f * red2[0] + 0.5f * (float)n * 1.8378770664093453f;
    }
}

// ---------------- host orchestration ----------------

// storeL=0: diag blocks end up holding Dinv (base case of L^{-1}); L kept off-diag.
// storeL=1: true L kept everywhere; Dinv staged through dscr.
static void run_chol(float* A, float* dscr, int storeL, hipStream_t stream) {
    for (int kb = 0; kb < 32; ++kb) {
        float* Ad = A + (size_t)kb * 64 * (NS + 1);
        float* dptr = storeL ? dscr : Ad;
        int dld = storeL ? 64 : NS;
        chol_diag_inv_k<<<1, 64, 0, stream>>>(Ad, NS, dptr, dld, storeL);
        int rem = NS - (kb + 1) * 64;
        if (rem > 0) {
            float* P = A + (size_t)(kb + 1) * 64 * NS + kb * 64;
            // panel: P = P @ Dinv^T  (in place)
            gemm64_k<0, 1><<<dim3(1, rem / 64), 256, 0, stream>>>(
                rem, 64, 64, P, NS, 0, dptr, dld, 0, P, NS, 0,
                nullptr, 0, nullptr, 0, 0, 0, 0);
            // trailing: C -= P P^T (lower only)
            float* Ct = A + (size_t)(kb + 1) * 64 * (NS + 1);
            gemm64_k<0, 1><<<dim3(rem / 64, rem / 64), 256, 0, stream>>>(
                rem, rem, 64, P, NS, 0, P, NS, 0, Ct, NS, 0,
                nullptr, 0, nullptr, 3, (kb + 1) * 64, (kb + 1) * 64, 1);
        }
    }
}

extern "C" void kernel_launch(void* const* d_in, const int* in_sizes, int n_in,
                              void* d_out, int out_size, void* d_ws, size_t ws_size,
                              hipStream_t stream) {
    const float* source_x = (const float*)d_in[0];
    const float* source_y = (const float*)d_in[1];
    const float* target_x = (const float*)d_in[2];
    const float* target_y = (const float*)d_in[3];
    const float* k_ss = (const float*)d_in[4];
    const float* k_tt = (const float*)d_in[5];
    const float* k_st = (const float*)d_in[6];
    const float* noise_s = (const float*)d_in[7];
    const float* noise_t = (const float*)d_in[8];
    const float* Wf = (const float*)d_in[9];
    const float* bf = (const float*)d_in[10];
    const float* Ws = (const float*)d_in[11];
    const float* bs = (const float*)d_in[12];
    const float* Wt = (const float*)d_in[13];
    const float* bt = (const float*)d_in[14];
    const float* Kb = (const float*)d_in[15];
    const float* base_s = (const float*)d_in[16];
    const float* base_t = (const float*)d_in[17];
    float* out = (float*)d_out;

    float* w = (float*)d_ws;
    const size_t M2 = (size_t)NS * NS;
    float* Ksrc = w;                 // K_src -> chol L -> Linv (in place)
    float* Kcos = w + M2;
    float* Ktgt = w + 2 * M2;        // K_tgt -> cov -> L_c
    float* stag = w + 3 * M2;        // wsb|wtb|wsK|wtK, later overlaid by Z
    float* wsb = stag;
    float* wtb = stag + (size_t)NS * NB;
    float* wsK = stag + 2 * (size_t)NS * NB;
    float* wtK = stag + 3 * (size_t)NS * NB;
    float* Z = stag;                 // 2048x2048, overlays staging
    float* T = w + 4 * M2;           // recursion temp, up to 1024^2
    float* sm = T + (size_t)1024 * 1024;
    float* wcomb = sm;               // 1024
    float* consts = sm + 1024;       // 4
    float* a_s = sm + 1032;          // 2048
    float* b_s = a_s + NS;           // 512
    float* a_t = b_s + NB;           // 2048
    float* b_t = a_t + NS;           // 512
    float* rvec = b_t + NB;          // 2048
    float* vvec = rvec + NS;         // 2048
    float* z2 = vvec + NS;           // 2048
    float* Dscr = z2 + NS;           // 4096

    // 1) feature maps + kernel weights
    prep_k<<<1, 256, 0, stream>>>(Wf, bf, Ws, Wt, wcomb, consts);
    matvec_k<<<NS / 4, 256, 0, stream>>>(source_x, NS, wcomb + 0 * DIMX, consts, 0, a_s);
    matvec_k<<<NB / 4, 256, 0, stream>>>(base_s, NB, wcomb + 1 * DIMX, consts, 1, b_s);
    matvec_k<<<NS / 4, 256, 0, stream>>>(target_x, NS, wcomb + 2 * DIMX, consts, 2, a_t);
    matvec_k<<<NB / 4, 256, 0, stream>>>(base_t, NB, wcomb + 3 * DIMX, consts, 3, b_t);
    weights_k<<<NS, 256, 0, stream>>>(a_s, b_s, bs, wsb);
    weights_k<<<NS, 256, 0, stream>>>(a_t, b_t, bt, wtb);

    // 2) wsK = ws@Kb, wtK = wt@Kb
    {
        dim3 g(NB / 128, NS / 128);
        gemm128_k<0, 0><<<g, 256, 0, stream>>>(NS, NB, NB, wsb, NB, 0, Kb, NB, 0, wsK, NB, 0,
                                               nullptr, 0, nullptr, 0, 0, 0, 0);
        gemm128_k<0, 0><<<g, 256, 0, stream>>>(NS, NB, NB, wtb, NB, 0, Kb, NB, 0, wtK, NB, 0,
                                               nullptr, 0, nullptr, 0, 0, 0, 0);
    }
    // 3) K_src, K_tgt, K_cos (Hadamard epilogues)
    {
        dim3 g(NS / 128, NS / 128);
        gemm128_k<0, 1><<<g, 256, 0, stream>>>(NS, NS, NB, wsK, NB, 0, wsb, NB, 0, Ksrc, NS, 0,
                                               k_ss, NS, noise_s, 1, 0, 0, 0);
        gemm128_k<0, 1><<<g, 256, 0, stream>>>(NS, NS, NB, wtK, NB, 0, wtb, NB, 0, Ktgt, NS, 0,
                                               k_tt, NS, noise_t, 1, 0, 0, 0);
        gemm128_k<0, 1><<<g, 256, 0, stream>>>(NS, NS, NB, wsK, NB, 0, wtb, NB, 0, Kcos, NS, 0,
                                               k_st, NS, nullptr, 2, 0, 0, 0);
    }

    // 4) Cholesky of K_src; diag blocks end as Dinv (base of Linv)
    run_chol(Ksrc, nullptr, 0, stream);

    // 5) zero strict upper, then in-place recursive triangular inversion:
    //    Linv_offdiag(2s) = -LinvC @ L_B @ LinvA, bottom-up
    zero_upper_k<<<NS, 256, 0, stream>>>(Ksrc, NS, NS);
    {
        // s = 64 level via gemm64 (16 pairs)
        size_t zz = (size_t)128 * (NS + 1);
        gemm64_k<0, 0><<<dim3(1, 1, 16), 256, 0, stream>>>(
            64, 64, 64, Ksrc + (size_t)64 * NS, NS, zz, Ksrc, NS, zz, T, 64, (size_t)4096,
            nullptr, 0, nullptr, 0, 0, 0, 0);
        gemm64_k<0, 0><<<dim3(1, 1, 16), 256, 0, stream>>>(
            64, 64, 64, Ksrc + (size_t)64 * (NS + 1), NS, zz, T, 64, (size_t)4096,
            Ksrc + (size_t)64 * NS, NS, zz, nullptr, 0, nullptr, 4, 0, 0, 0);
    }
    for (int s = 128; s <= 1024; s <<= 1) {
        int np = NS / (2 * s);
        size_t zz = (size_t)2 * s * (NS + 1);
        size_t zt = (size_t)s * s;
        dim3 g(s / 128, s / 128, np);
        gemm128_k<0, 0><<<g, 256, 0, stream>>>(s, s, s, Ksrc + (size_t)s * NS, NS, zz,
                                               Ksrc, NS, zz, T, s, zt,
                                               nullptr, 0, nullptr, 0, 0, 0, 0);
        gemm128_k<0, 0><<<g, 256, 0, stream>>>(s, s, s, Ksrc + (size_t)s * (NS + 1), NS, zz,
                                               T, s, zt, Ksrc + (size_t)s * NS, NS, zz,
                                               nullptr, 0, nullptr, 4, 0, 0, 0);
    }

    // 6) Z = Linv @ Kcos (K trimmed to the lower band)
    {
        dim3 g(NS / 128, NS / 128);
        gemm128_k<0, 0><<<g, 256, 0, stream>>>(NS, NS, NS, Ksrc, NS, 0, Kcos, NS, 0, Z, NS, 0,
                                               nullptr, 0, nullptr, 0, 0, 0, 2);
    }

    // 7) z2 = Linv @ source_y ; r = target_y - Z^T z2
    gemv_lower_k<<<NS / 4, 256, 0, stream>>>(Ksrc, NS, source_y, z2, NS);
    resid_k<<<NS / 256, 256, 0, stream>>>(Z, NS, z2, target_y, rvec);

    // 8) cov = K_tgt - Z^T Z (lower only)
    {
        dim3 g(NS / 128, NS / 128);
        gemm128_k<1, 0><<<g, 256, 0, stream>>>(NS, NS, NS, Z, NS, 0, Z, NS, 0, Ktgt, NS, 0,
                                               nullptr, 0, nullptr, 3, 0, 0, 1);
    }

    // 9) Cholesky of cov (true L kept)
    run_chol(Ktgt, Dscr, 1, stream);

    // 10) v = Lc^{-1} r ; loss
    trsv_fwd_k<<<1, 64, 0, stream>>>(Ktgt, NS, NS, rvec, vvec);
    loss_k<<<1, 256, 0, stream>>>(Ktgt, NS, NS, vvec, out);
}

// Round 3
// 14694.933 us; speedup vs baseline: 1.9980x; 1.5012x over previous
//
#include <hip/hip_runtime.h>
#include <hip/hip_bf16.h>
#include <math.h>

#define NS 2048
#define NB 512
#define DIMX 256
#define NFEAT 8

// ---------------- small prep kernels ----------------

__global__ __launch_bounds__(256) void prep_k(const float* __restrict__ Wf,
                                              const float* __restrict__ bf,
                                              const float* __restrict__ Ws,
                                              const float* __restrict__ Wt,
                                              float* __restrict__ wcomb,
                                              float* __restrict__ consts) {
    int d = threadIdx.x;
    float w0 = 0.f, w1 = 0.f, w2 = 0.f, w3 = 0.f;
#pragma unroll
    for (int k = 0; k < NFEAT; ++k) {
        float wf = Wf[k * DIMX + d];
        w0 += Ws[k] * wf;
        w1 += Ws[NFEAT + k] * wf;
        w2 += Wt[k] * wf;
        w3 += Wt[NFEAT + k] * wf;
    }
    wcomb[0 * DIMX + d] = w0;
    wcomb[1 * DIMX + d] = w1;
    wcomb[2 * DIMX + d] = w2;
    wcomb[3 * DIMX + d] = w3;
    if (d == 0) {
        float c0 = 0.f, c1 = 0.f, c2 = 0.f, c3 = 0.f;
#pragma unroll
        for (int k = 0; k < NFEAT; ++k) {
            c0 += Ws[k] * bf[k];
            c1 += Ws[NFEAT + k] * bf[k];
            c2 += Wt[k] * bf[k];
            c3 += Wt[NFEAT + k] * bf[k];
        }
        consts[0] = c0; consts[1] = c1; consts[2] = c2; consts[3] = c3;
    }
}

__global__ __launch_bounds__(256) void matvec_k(const float* __restrict__ X, int nrows,
                                                const float* __restrict__ wc,
                                                const float* __restrict__ consts, int cidx,
                                                float* __restrict__ out) {
    int wave = threadIdx.x >> 6, lane = threadIdx.x & 63;
    int row = blockIdx.x * 4 + wave;
    if (row >= nrows) return;
    const float* xr = X + (size_t)row * DIMX;
    float s = 0.f;
#pragma unroll
    for (int t = 0; t < 4; ++t) s += xr[lane + 64 * t] * wc[lane + 64 * t];
#pragma unroll
    for (int off = 32; off; off >>= 1) s += __shfl_down(s, off);
    if (lane == 0) out[row] = s + consts[cidx];
}

__global__ __launch_bounds__(256) void weights_k(const float* __restrict__ a,
                                                 const float* __restrict__ b,
                                                 const float* __restrict__ bw,
                                                 float* __restrict__ w) {
    __shared__ float red[256];
    int i = blockIdx.x, tid = threadIdx.x;
    float ai = a[i] + bw[0];
    float r1 = ai + b[tid];
    float r2 = ai + b[tid + 256];
    float e1 = r1 > 0.f ? r1 : expm1f(r1);
    float e2 = r2 > 0.f ? r2 : expm1f(r2);
    red[tid] = e1 + e2;
    __syncthreads();
    for (int s = 128; s; s >>= 1) {
        if (tid < s) red[tid] += red[tid + s];
        __syncthreads();
    }
    float scale = 512.f / red[0];
    w[(size_t)i * NB + tid] = e1 * scale;
    w[(size_t)i * NB + tid + 256] = e2 * scale;
}

// ---------------- 64-tile f32 GEMM (thin work, batched-z) ----------------
// mode 0: C=acc | 1: C=kmat*acc+diag(noise) | 2: C=kmat*acc | 3: C=C-acc | 4: C=-acc
template <int TA, int TB>
__global__ __launch_bounds__(256) void gemm64_k(int M, int N, int K,
                                                const float* __restrict__ A, int lda, size_t zoffA,
                                                const float* __restrict__ B, int ldb, size_t zoffB,
                                                float* __restrict__ C, int ldc, size_t zoffC,
                                                const float* __restrict__ kmat, int ldk,
                                                const float* __restrict__ noisep,
                                                int mode, int row0, int col0, int lower_only) {
    __shared__ float As[16][65];
    __shared__ float Bs[16][65];
    int bz = blockIdx.z;
    A += zoffA * bz; B += zoffB * bz; C += zoffC * bz;
    int bm = blockIdx.y, bn = blockIdx.x;
    int rowBase = bm * 64, colBase = bn * 64;
    if (lower_only && (row0 + rowBase + 63) < (col0 + colBase)) return;
    int tid = threadIdx.x;
    int tx = tid & 15, ty = tid >> 4;
    float acc[4][4];
#pragma unroll
    for (int i = 0; i < 4; ++i)
#pragma unroll
        for (int j = 0; j < 4; ++j) acc[i][j] = 0.f;

    for (int kk = 0; kk < K; kk += 16) {
        if (TA == 0) {
#pragma unroll
            for (int t = tid; t < 64 * 16; t += 256) {
                int k = t & 15, i = t >> 4;
                int gi = rowBase + i, gk = kk + k;
                As[k][i] = (gi < M && gk < K) ? A[(size_t)gi * lda + gk] : 0.f;
            }
        } else {
#pragma unroll
            for (int t = tid; t < 64 * 16; t += 256) {
                int i = t & 63, k = t >> 6;
                int gi = rowBase + i, gk = kk + k;
                As[k][i] = (gi < M && gk < K) ? A[(size_t)gk * lda + gi] : 0.f;
            }
        }
        if (TB == 0) {
#pragma unroll
            for (int t = tid; t < 64 * 16; t += 256) {
                int j = t & 63, k = t >> 6;
                int gj = colBase + j, gk = kk + k;
                Bs[k][j] = (gj < N && gk < K) ? B[(size_t)gk * ldb + gj] : 0.f;
            }
        } else {
#pragma unroll
            for (int t = tid; t < 64 * 16; t += 256) {
                int k = t & 15, j = t >> 4;
                int gj = colBase + j, gk = kk + k;
                Bs[k][j] = (gj < N && gk < K) ? B[(size_t)gj * ldb + gk] : 0.f;
            }
        }
        __syncthreads();
#pragma unroll
        for (int k = 0; k < 16; ++k) {
            float a0 = As[k][ty * 4 + 0], a1 = As[k][ty * 4 + 1];
            float a2 = As[k][ty * 4 + 2], a3 = As[k][ty * 4 + 3];
            float b0 = Bs[k][tx * 4 + 0], b1 = Bs[k][tx * 4 + 1];
            float b2 = Bs[k][tx * 4 + 2], b3 = Bs[k][tx * 4 + 3];
            acc[0][0] += a0 * b0; acc[0][1] += a0 * b1; acc[0][2] += a0 * b2; acc[0][3] += a0 * b3;
            acc[1][0] += a1 * b0; acc[1][1] += a1 * b1; acc[1][2] += a1 * b2; acc[1][3] += a1 * b3;
            acc[2][0] += a2 * b0; acc[2][1] += a2 * b1; acc[2][2] += a2 * b2; acc[2][3] += a2 * b3;
            acc[3][0] += a3 * b0; acc[3][1] += a3 * b1; acc[3][2] += a3 * b2; acc[3][3] += a3 * b3;
        }
        __syncthreads();
    }
#pragma unroll
    for (int i = 0; i < 4; ++i) {
#pragma unroll
        for (int j = 0; j < 4; ++j) {
            int gi = rowBase + ty * 4 + i, gj = colBase + tx * 4 + j;
            if (gi < M && gj < N) {
                float v = acc[i][j];
                if (mode == 1 || mode == 2) {
                    v *= kmat[(size_t)gi * ldk + gj];
                    if (mode == 1 && (row0 + gi) == (col0 + gj)) {
                        float ns = noisep[0];
                        ns = fminf(fmaxf(ns, 1e-5f), 1.0f);
                        v += ns;
                    }
                } else if (mode == 3) {
                    v = C[(size_t)gi * ldc + gj] - v;
                } else if (mode == 4) {
                    v = -v;
                }
                C[(size_t)gi * ldc + gj] = v;
            }
        }
    }
}

// ---------------- 128-tile f32 GEMM (exact multiples of 128 in M,N; K mult of 16) ----
// flags bit0 = lower_only (skip tiles strictly above diagonal)
// flags bit1 = ktrim (K limited to rowBase+128; for lower-triangular A)
template <int TA, int TB>
__global__ __launch_bounds__(256) void gemm128_k(int M, int N, int K,
                                                 const float* __restrict__ A, int lda, size_t zoffA,
                                                 const float* __restrict__ B, int ldb, size_t zoffB,
                                                 float* __restrict__ C, int ldc, size_t zoffC,
                                                 const float* __restrict__ kmat, int ldk,
                                                 const float* __restrict__ noisep,
                                                 int mode, int row0, int col0, int flags) {
    __shared__ float As[16][132];
    __shared__ float Bs[16][132];
    int bz = blockIdx.z;
    A += zoffA * bz; B += zoffB * bz; C += zoffC * bz;
    int bm = blockIdx.y, bn = blockIdx.x;
    int rowBase = bm * 128, colBase = bn * 128;
    if ((flags & 1) && (rowBase + 127) < colBase) return;
    int Kend = (flags & 2) ? ((rowBase + 128 < K) ? rowBase + 128 : K) : K;
    int tid = threadIdx.x;
    int tx = tid & 15, ty = tid >> 4;
    float acc[8][8];
#pragma unroll
    for (int i = 0; i < 8; ++i)
#pragma unroll
        for (int j = 0; j < 8; ++j) acc[i][j] = 0.f;

    for (int kk = 0; kk < Kend; kk += 16) {
        if (TA == 0) {
            int row = tid >> 1, koff = (tid & 1) * 8;
            const float* src = A + (size_t)(rowBase + row) * lda + kk + koff;
            float4 v0 = *(const float4*)(src);
            float4 v1 = *(const float4*)(src + 4);
            As[koff + 0][row] = v0.x; As[koff + 1][row] = v0.y;
            As[koff + 2][row] = v0.z; As[koff + 3][row] = v0.w;
            As[koff + 4][row] = v1.x; As[koff + 5][row] = v1.y;
            As[koff + 6][row] = v1.z; As[koff + 7][row] = v1.w;
        } else {
            int k = tid >> 4, ib = (tid & 15) * 4;
            const float* src = A + (size_t)(kk + k) * lda + rowBase + ib;
            *(float4*)&As[k][ib] = *(const float4*)src;
            *(float4*)&As[k][ib + 64] = *(const float4*)(src + 64);
        }
        if (TB == 0) {
            int k = tid >> 4, jb = (tid & 15) * 4;
            const float* src = B + (size_t)(kk + k) * ldb + colBase + jb;
            *(float4*)&Bs[k][jb] = *(const float4*)src;
            *(float4*)&Bs[k][jb + 64] = *(const float4*)(src + 64);
        } else {
            int col = tid >> 1, koff = (tid & 1) * 8;
            const float* src = B + (size_t)(colBase + col) * ldb + kk + koff;
            float4 v0 = *(const float4*)(src);
            float4 v1 = *(const float4*)(src + 4);
            Bs[koff + 0][col] = v0.x; Bs[koff + 1][col] = v0.y;
            Bs[koff + 2][col] = v0.z; Bs[koff + 3][col] = v0.w;
            Bs[koff + 4][col] = v1.x; Bs[koff + 5][col] = v1.y;
            Bs[koff + 6][col] = v1.z; Bs[koff + 7][col] = v1.w;
        }
        __syncthreads();
#pragma unroll
        for (int k = 0; k < 16; ++k) {
            float a[8], b[8];
            float4 t0 = *(const float4*)&As[k][ty * 4];
            float4 t1 = *(const float4*)&As[k][64 + ty * 4];
            float4 u0 = *(const float4*)&Bs[k][tx * 4];
            float4 u1 = *(const float4*)&Bs[k][64 + tx * 4];
            a[0] = t0.x; a[1] = t0.y; a[2] = t0.z; a[3] = t0.w;
            a[4] = t1.x; a[5] = t1.y; a[6] = t1.z; a[7] = t1.w;
            b[0] = u0.x; b[1] = u0.y; b[2] = u0.z; b[3] = u0.w;
            b[4] = u1.x; b[5] = u1.y; b[6] = u1.z; b[7] = u1.w;
#pragma unroll
            for (int i = 0; i < 8; ++i)
#pragma unroll
                for (int j = 0; j < 8; ++j) acc[i][j] += a[i] * b[j];
        }
        __syncthreads();
    }
#pragma unroll
    for (int i = 0; i < 8; ++i) {
        int gi = rowBase + ((i >> 2) << 6) + ty * 4 + (i & 3);
#pragma unroll
        for (int j = 0; j < 8; ++j) {
            int gj = colBase + ((j >> 2) << 6) + tx * 4 + (j & 3);
            float v = acc[i][j];
            if (mode == 1 || mode == 2) {
                v *= kmat[(size_t)gi * ldk + gj];
                if (mode == 1 && (row0 + gi) == (col0 + gj)) {
                    float ns = noisep[0];
                    ns = fminf(fmaxf(ns, 1e-5f), 1.0f);
                    v += ns;
                }
            } else if (mode == 3) {
                v = C[(size_t)gi * ldc + gj] - v;
            } else if (mode == 4) {
                v = -v;
            }
            C[(size_t)gi * ldc + gj] = v;
        }
    }
}

// ---------------- fused 64x64 diag Cholesky + triangular inverse ----------------
// Writes Dinv (= inverse of the diag Cholesky factor, full 64x64 incl. zeros) back
// into the diag block of A. Off-diag L panels are kept elsewhere.
__global__ __launch_bounds__(64) void chol_diag_inv_k(float* __restrict__ A, int lda) {
    __shared__ float s[64][65];
    __shared__ float X[64][65];
    int tid = threadIdx.x;
    for (int r = 0; r < 64; ++r) s[r][tid] = A[(size_t)r * lda + tid];
    __syncthreads();
    for (int k = 0; k < 64; ++k) {
        float dk = sqrtf(s[k][k]);
        float inv = 1.0f / dk;
        if (tid == k) s[k][k] = dk;
        if (tid > k) s[tid][k] *= inv;
        __syncthreads();
        if (tid > k) {
            float aik = s[tid][k];
            for (int j = k + 1; j <= tid; ++j) s[tid][j] -= aik * s[j][k];
        }
        __syncthreads();
    }
    // invert lower-tri L (in s): column tid of X = L^{-1}
    for (int r = 0; r < 64; ++r) {
        if (r < tid) {
            X[r][tid] = 0.f;
        } else if (r == tid) {
            X[r][tid] = 1.0f / s[r][r];
        } else {
            float acc = 0.f;
            for (int t = tid; t < r; ++t) acc -= s[r][t] * X[t][tid];
            X[r][tid] = acc / s[r][r];
        }
    }
    __syncthreads();
    for (int r = 0; r < 64; ++r) A[(size_t)r * lda + tid] = X[r][tid];
}

__global__ __launch_bounds__(256) void zero_upper_k(float* __restrict__ A, int n, int lda) {
    int i = blockIdx.x;
    for (int j = i + 1 + threadIdx.x; j < n; j += 256) A[(size_t)i * lda + j] = 0.f;
}

// z[row] = sum_{j<=row} L[row][j] * y[j]
__global__ __launch_bounds__(256) void gemv_lower_k(const float* __restrict__ L, int ld,
                                                    const float* __restrict__ y,
                                                    float* __restrict__ z, int n) {
    int wave = threadIdx.x >> 6, lane = threadIdx.x & 63;
    int row = blockIdx.x * 4 + wave;
    if (row >= n) return;
    const float* Lr = L + (size_t)row * ld;
    float s = 0.f;
    for (int j = lane; j <= row; j += 64) s += Lr[j] * y[j];
#pragma unroll
    for (int off = 32; off; off >>= 1) s += __shfl_down(s, off);
    if (lane == 0) z[row] = s;
}

// r[j] = ty[j] - sum_i Z[i][j] * zv[i]
__global__ __launch_bounds__(256) void resid_k(const float* __restrict__ Z, int n,
                                               const float* __restrict__ zv,
                                               const float* __restrict__ ty,
                                               float* __restrict__ r) {
    int j = blockIdx.x * 256 + threadIdx.x;
    float acc = 0.f;
    for (int i = 0; i < n; ++i) acc += Z[(size_t)i * n + j] * zv[i];
    r[j] = ty[j] - acc;
}

// loss = 0.5*sign*sum(log(diag)) + 0.5*||v||^2 + 0.5*n*log(2*pi)
__global__ __launch_bounds__(256) void loss_k(const float* __restrict__ Lc, int n, int ldl,
                                              float sign,
                                              const float* __restrict__ v,
                                              float* __restrict__ out) {
    __shared__ float red1[256];
    __shared__ float red2[256];
    int tid = threadIdx.x;
    float s1 = 0.f, s2 = 0.f;
    for (int i = tid; i < n; i += 256) {
        s1 += logf(Lc[(size_t)i * ldl + i]);
        float vi = v[i];
        s2 += vi * vi;
    }
    red1[tid] = s1;
    red2[tid] = s2;
    __syncthreads();
    for (int s = 128; s; s >>= 1) {
        if (tid < s) { red1[tid] += red1[tid + s]; red2[tid] += red2[tid + s]; }
        __syncthreads();
    }
    if (tid == 0) {
        out[0] = 0.5f * sign * red1[0] + 0.5f * red2[0] + 0.5f * (float)n * 1.8378770664093453f;
    }
}

// ---------------- host orchestration ----------------

// Blocked right-looking Cholesky, BS=64. On exit: off-diag lower blocks hold L,
// diag blocks hold Dinv (inverse of the 64x64 diagonal Cholesky factors).
static void run_chol(float* A, hipStream_t stream) {
    for (int kb = 0; kb < 32; ++kb) {
        float* Ad = A + (size_t)kb * 64 * (NS + 1);
        chol_diag_inv_k<<<1, 64, 0, stream>>>(Ad, NS);
        int rem = NS - (kb + 1) * 64;
        if (rem > 0) {
            float* P = A + (size_t)(kb + 1) * 64 * NS + kb * 64;
            // panel: P = P @ Dinv^T  (in place)
            gemm64_k<0, 1><<<dim3(1, rem / 64), 256, 0, stream>>>(
                rem, 64, 64, P, NS, 0, Ad, NS, 0, P, NS, 0,
                nullptr, 0, nullptr, 0, 0, 0, 0);
            // trailing: C -= P P^T (lower only)
            float* Ct = A + (size_t)(kb + 1) * 64 * (NS + 1);
            gemm64_k<0, 1><<<dim3(rem / 64, rem / 64), 256, 0, stream>>>(
                rem, rem, 64, P, NS, 0, P, NS, 0, Ct, NS, 0,
                nullptr, 0, nullptr, 3, (kb + 1) * 64, (kb + 1) * 64, 1);
        }
    }
}

// In-place recursive inversion of the lower-triangular factor stored in A
// (diag blocks already hold Dinv from run_chol). T = scratch >= 1024^2 floats.
static void run_inv(float* A, float* T, hipStream_t stream) {
    zero_upper_k<<<NS, 256, 0, stream>>>(A, NS, NS);
    {
        size_t zz = (size_t)128 * (NS + 1);
        gemm64_k<0, 0><<<dim3(1, 1, 16), 256, 0, stream>>>(
            64, 64, 64, A + (size_t)64 * NS, NS, zz, A, NS, zz, T, 64, (size_t)4096,
            nullptr, 0, nullptr, 0, 0, 0, 0);
        gemm64_k<0, 0><<<dim3(1, 1, 16), 256, 0, stream>>>(
            64, 64, 64, A + (size_t)64 * (NS + 1), NS, zz, T, 64, (size_t)4096,
            A + (size_t)64 * NS, NS, zz, nullptr, 0, nullptr, 4, 0, 0, 0);
    }
    for (int s = 128; s <= 1024; s <<= 1) {
        int np = NS / (2 * s);
        size_t zz = (size_t)2 * s * (NS + 1);
        size_t zt = (size_t)s * s;
        dim3 g(s / 128, s / 128, np);
        gemm128_k<0, 0><<<g, 256, 0, stream>>>(s, s, s, A + (size_t)s * NS, NS, zz,
                                               A, NS, zz, T, s, zt,
                                               nullptr, 0, nullptr, 0, 0, 0, 0);
        gemm128_k<0, 0><<<g, 256, 0, stream>>>(s, s, s, A + (size_t)s * (NS + 1), NS, zz,
                                               T, s, zt, A + (size_t)s * NS, NS, zz,
                                               nullptr, 0, nullptr, 4, 0, 0, 0);
    }
}

extern "C" void kernel_launch(void* const* d_in, const int* in_sizes, int n_in,
                              void* d_out, int out_size, void* d_ws, size_t ws_size,
                              hipStream_t stream) {
    const float* source_x = (const float*)d_in[0];
    const float* source_y = (const float*)d_in[1];
    const float* target_x = (const float*)d_in[2];
    const float* target_y = (const float*)d_in[3];
    const float* k_ss = (const float*)d_in[4];
    const float* k_tt = (const float*)d_in[5];
    const float* k_st = (const float*)d_in[6];
    const float* noise_s = (const float*)d_in[7];
    const float* noise_t = (const float*)d_in[8];
    const float* Wf = (const float*)d_in[9];
    const float* bf = (const float*)d_in[10];
    const float* Ws = (const float*)d_in[11];
    const float* bs = (const float*)d_in[12];
    const float* Wt = (const float*)d_in[13];
    const float* bt = (const float*)d_in[14];
    const float* Kb = (const float*)d_in[15];
    const float* base_s = (const float*)d_in[16];
    const float* base_t = (const float*)d_in[17];
    float* out = (float*)d_out;

    float* w = (float*)d_ws;
    const size_t M2 = (size_t)NS * NS;
    float* Ksrc = w;                 // K_src -> chol -> Linv (in place)
    float* Kcos = w + M2;
    float* Ktgt = w + 2 * M2;        // K_tgt -> cov -> Lc -> Lcinv (in place)
    float* stag = w + 3 * M2;        // wsb|wtb|wsK|wtK, later overlaid by Z
    float* wsb = stag;
    float* wtb = stag + (size_t)NS * NB;
    float* wsK = stag + 2 * (size_t)NS * NB;
    float* wtK = stag + 3 * (size_t)NS * NB;
    float* Z = stag;                 // 2048x2048, overlays staging
    float* T = w + 4 * M2;           // recursion temp, up to 1024^2
    float* sm = T + (size_t)1024 * 1024;
    float* wcomb = sm;               // 1024
    float* consts = sm + 1024;       // 4
    float* a_s = sm + 1032;          // 2048
    float* b_s = a_s + NS;           // 512
    float* a_t = b_s + NB;           // 2048
    float* b_t = a_t + NS;           // 512
    float* rvec = b_t + NB;          // 2048
    float* vvec = rvec + NS;         // 2048
    float* z2 = vvec + NS;           // 2048

    // 1) feature maps + kernel weights
    prep_k<<<1, 256, 0, stream>>>(Wf, bf, Ws, Wt, wcomb, consts);
    matvec_k<<<NS / 4, 256, 0, stream>>>(source_x, NS, wcomb + 0 * DIMX, consts, 0, a_s);
    matvec_k<<<NB / 4, 256, 0, stream>>>(base_s, NB, wcomb + 1 * DIMX, consts, 1, b_s);
    matvec_k<<<NS / 4, 256, 0, stream>>>(target_x, NS, wcomb + 2 * DIMX, consts, 2, a_t);
    matvec_k<<<NB / 4, 256, 0, stream>>>(base_t, NB, wcomb + 3 * DIMX, consts, 3, b_t);
    weights_k<<<NS, 256, 0, stream>>>(a_s, b_s, bs, wsb);
    weights_k<<<NS, 256, 0, stream>>>(a_t, b_t, bt, wtb);

    // 2) wsK = ws@Kb, wtK = wt@Kb
    {
        dim3 g(NB / 128, NS / 128);
        gemm128_k<0, 0><<<g, 256, 0, stream>>>(NS, NB, NB, wsb, NB, 0, Kb, NB, 0, wsK, NB, 0,
                                               nullptr, 0, nullptr, 0, 0, 0, 0);
        gemm128_k<0, 0><<<g, 256, 0, stream>>>(NS, NB, NB, wtb, NB, 0, Kb, NB, 0, wtK, NB, 0,
                                               nullptr, 0, nullptr, 0, 0, 0, 0);
    }
    // 3) K_src, K_tgt, K_cos (Hadamard epilogues)
    {
        dim3 g(NS / 128, NS / 128);
        gemm128_k<0, 1><<<g, 256, 0, stream>>>(NS, NS, NB, wsK, NB, 0, wsb, NB, 0, Ksrc, NS, 0,
                                               k_ss, NS, noise_s, 1, 0, 0, 0);
        gemm128_k<0, 1><<<g, 256, 0, stream>>>(NS, NS, NB, wtK, NB, 0, wtb, NB, 0, Ktgt, NS, 0,
                                               k_tt, NS, noise_t, 1, 0, 0, 0);
        gemm128_k<0, 1><<<g, 256, 0, stream>>>(NS, NS, NB, wsK, NB, 0, wtb, NB, 0, Kcos, NS, 0,
                                               k_st, NS, nullptr, 2, 0, 0, 0);
    }

    // 4) Cholesky of K_src + full triangular inversion -> Linv in Ksrc
    run_chol(Ksrc, stream);
    run_inv(Ksrc, T, stream);

    // 5) Z = Linv @ Kcos (K trimmed to the lower band)
    {
        dim3 g(NS / 128, NS / 128);
        gemm128_k<0, 0><<<g, 256, 0, stream>>>(NS, NS, NS, Ksrc, NS, 0, Kcos, NS, 0, Z, NS, 0,
                                               nullptr, 0, nullptr, 0, 0, 0, 2);
    }

    // 6) z2 = Linv @ source_y ; r = target_y - Z^T z2
    gemv_lower_k<<<NS / 4, 256, 0, stream>>>(Ksrc, NS, source_y, z2, NS);
    resid_k<<<NS / 256, 256, 0, stream>>>(Z, NS, z2, target_y, rvec);

    // 7) cov = K_tgt - Z^T Z (lower only)
    {
        dim3 g(NS / 128, NS / 128);
        gemm128_k<1, 0><<<g, 256, 0, stream>>>(NS, NS, NS, Z, NS, 0, Z, NS, 0, Ktgt, NS, 0,
                                               nullptr, 0, nullptr, 3, 0, 0, 1);
    }

    // 8) Cholesky of cov + full triangular inversion -> Lcinv in Ktgt
    run_chol(Ktgt, stream);
    run_inv(Ktgt, T, stream);

    // 9) v = Lcinv @ r ; loss (log diag(Lc) = -log diag(Lcinv))
    gemv_lower_k<<<NS / 4, 256, 0, stream>>>(Ktgt, NS, rvec, vvec, NS);
    loss_k<<<1, 256, 0, stream>>>(Ktgt, NS, NS, -1.0f, vvec, out);
}